// Round 1
// baseline (134.451 us; speedup 1.0000x reference)
//
#include <hip/hip_runtime.h>

// Problem: B=128, L=8192, C=8. loss = 1 - mean_over_rows( all_c(real == (pred>0.5)) )
// real, pred: float32 [B*L*C], C=8 innermost & contiguous -> 32 B/row.

#define N_ROWS (128 * 8192)
#define BLOCK 256

__global__ __launch_bounds__(BLOCK) void row_match_count(
    const float4* __restrict__ real4,
    const float4* __restrict__ pred4,
    unsigned int* __restrict__ count) {
  int row = blockIdx.x * BLOCK + threadIdx.x;

  // Each row = 8 floats = 2 x float4 per array.
  float4 r0 = real4[2 * row];
  float4 r1 = real4[2 * row + 1];
  float4 p0 = pred4[2 * row];
  float4 p1 = pred4[2 * row + 1];

  // real is exactly 0.0f or 1.0f, so (real == (pred>0.5)) <=> ((real>0.5)==(pred>0.5)).
  bool ok = ((r0.x > 0.5f) == (p0.x > 0.5f)) &&
            ((r0.y > 0.5f) == (p0.y > 0.5f)) &&
            ((r0.z > 0.5f) == (p0.z > 0.5f)) &&
            ((r0.w > 0.5f) == (p0.w > 0.5f)) &&
            ((r1.x > 0.5f) == (p1.x > 0.5f)) &&
            ((r1.y > 0.5f) == (p1.y > 0.5f)) &&
            ((r1.z > 0.5f) == (p1.z > 0.5f)) &&
            ((r1.w > 0.5f) == (p1.w > 0.5f));

  // Wave-level reduce: 64-bit ballot + popcount (wave = 64 on CDNA).
  unsigned long long mask = __ballot(ok);
  int lane = threadIdx.x & 63;
  int wave = threadIdx.x >> 6;

  __shared__ unsigned int wsum[BLOCK / 64];
  if (lane == 0) wsum[wave] = (unsigned int)__popcll(mask);
  __syncthreads();

  if (threadIdx.x == 0) {
    unsigned int s = 0;
#pragma unroll
    for (int i = 0; i < BLOCK / 64; ++i) s += wsum[i];
    atomicAdd(count, s);  // one atomic per block (4096 blocks total)
  }
}

__global__ void finalize_loss(const unsigned int* __restrict__ count,
                              float* __restrict__ out) {
  out[0] = 1.0f - (float)(*count) * (1.0f / (float)N_ROWS);
}

extern "C" void kernel_launch(void* const* d_in, const int* in_sizes, int n_in,
                              void* d_out, int out_size, void* d_ws, size_t ws_size,
                              hipStream_t stream) {
  const float4* real4 = (const float4*)d_in[0];
  const float4* pred4 = (const float4*)d_in[1];
  unsigned int* count = (unsigned int*)d_ws;  // 4 bytes of scratch
  float* out = (float*)d_out;

  // d_ws is poisoned to 0xAA before every timed launch — zero the counter.
  hipMemsetAsync(count, 0, sizeof(unsigned int), stream);

  int grid = N_ROWS / BLOCK;  // 1,048,576 rows / 256 = 4096 blocks, exact
  row_match_count<<<grid, BLOCK, 0, stream>>>(real4, pred4, count);
  finalize_loss<<<1, 1, 0, stream>>>(count, out);
}

// Round 2
// 92.751 us; speedup vs baseline: 1.4496x; 1.4496x over previous
//
#include <hip/hip_runtime.h>

// loss = 1 - mean_over_rows( all_c(real == (pred>0.5)) ), real/pred f32 [128,8192,8]
// C=8 contiguous -> one float4 = half a row. Unit-stride float4 indexing across
// the wave; halves of row k land in lanes 2k,2k+1 -> pair them with ballot bits.

#define N_ROWS (128 * 8192)              // 1,048,576 rows
#define N_F4   (N_ROWS * 2)              // 2,097,152 float4s per input
#define BLOCK  256
#define ITERS  4
#define GRID   (N_F4 / (BLOCK * ITERS))  // 2048 blocks, exact

__global__ __launch_bounds__(BLOCK) void row_match_count(
    const float4* __restrict__ real4,
    const float4* __restrict__ pred4,
    unsigned int* __restrict__ partials) {
  const int base = blockIdx.x * (BLOCK * ITERS) + threadIdx.x;

  // 8 independent coalesced 16B loads in flight before any use.
  float4 r[ITERS], p[ITERS];
#pragma unroll
  for (int j = 0; j < ITERS; ++j) r[j] = real4[base + j * BLOCK];
#pragma unroll
  for (int j = 0; j < ITERS; ++j) p[j] = pred4[base + j * BLOCK];

  unsigned int cnt = 0;
#pragma unroll
  for (int j = 0; j < ITERS; ++j) {
    // real is exactly 0/1: (real == (pred>0.5)) <=> ((real>0.5)==(pred>0.5))
    bool ok = ((r[j].x > 0.5f) == (p[j].x > 0.5f)) &&
              ((r[j].y > 0.5f) == (p[j].y > 0.5f)) &&
              ((r[j].z > 0.5f) == (p[j].z > 0.5f)) &&
              ((r[j].w > 0.5f) == (p[j].w > 0.5f));
    // 64-bit wave ballot: bit i = lane i's half-row ok. Row ok = both halves ok.
    unsigned long long m = __ballot(ok);
    m &= (m >> 1);
    m &= 0x5555555555555555ULL;
    cnt += (unsigned int)__popcll(m);  // wave-uniform: rows matched this iter
  }

  // Combine the 4 waves of the block; one partial per block, NO global atomic.
  __shared__ unsigned int wsum[BLOCK / 64];
  const int lane = threadIdx.x & 63;
  const int wave = threadIdx.x >> 6;
  if (lane == 0) wsum[wave] = cnt;
  __syncthreads();
  if (threadIdx.x == 0)
    partials[blockIdx.x] = wsum[0] + wsum[1] + wsum[2] + wsum[3];
}

__global__ __launch_bounds__(64) void finalize_loss(
    const unsigned int* __restrict__ partials, float* __restrict__ out) {
  unsigned int s = 0;
  const int lane = threadIdx.x;  // 64 threads, coalesced strided sum of 2048 partials
#pragma unroll
  for (int k = 0; k < GRID / 64; ++k) s += partials[lane + k * 64];
#pragma unroll
  for (int off = 32; off > 0; off >>= 1) s += __shfl_down(s, off, 64);
  if (lane == 0) out[0] = 1.0f - (float)s * (1.0f / (float)N_ROWS);
}

extern "C" void kernel_launch(void* const* d_in, const int* in_sizes, int n_in,
                              void* d_out, int out_size, void* d_ws, size_t ws_size,
                              hipStream_t stream) {
  const float4* real4 = (const float4*)d_in[0];
  const float4* pred4 = (const float4*)d_in[1];
  unsigned int* partials = (unsigned int*)d_ws;  // 2048 * 4 B = 8 KB scratch
  float* out = (float*)d_out;

  // Every partial slot is written by its block -> no memset node needed.
  row_match_count<<<GRID, BLOCK, 0, stream>>>(real4, pred4, partials);
  finalize_loss<<<1, 64, 0, stream>>>(partials, out);
}

// Round 3
// 91.999 us; speedup vs baseline: 1.4614x; 1.0082x over previous
//
#include <hip/hip_runtime.h>

// loss = 1 - mean_over_rows( all_c(real == (pred>0.5)) ), real/pred f32 [128,8192,8]
// C=8 contiguous -> one float4 = half a row. Unit-stride float4 indexing across
// the wave; halves of row k land in lanes 2k,2k+1 -> paired via ballot bits.

#define N_ROWS (128 * 8192)              // 1,048,576 rows
#define N_F4   (N_ROWS * 2)              // 2,097,152 float4s per input
#define BLOCK  256
#define ITERS  8
#define GRID   (N_F4 / (BLOCK * ITERS))  // 1024 blocks, exact

__global__ __launch_bounds__(BLOCK) void row_match_count(
    const float4* __restrict__ real4,
    const float4* __restrict__ pred4,
    unsigned int* __restrict__ partials) {
  const int base = blockIdx.x * (BLOCK * ITERS) + threadIdx.x;

  // 16 independent coalesced 16B loads in flight before any use (MLP).
  float4 r[ITERS], p[ITERS];
#pragma unroll
  for (int j = 0; j < ITERS; ++j) r[j] = real4[base + j * BLOCK];
#pragma unroll
  for (int j = 0; j < ITERS; ++j) p[j] = pred4[base + j * BLOCK];

  unsigned int cnt = 0;
#pragma unroll
  for (int j = 0; j < ITERS; ++j) {
    // real is exactly 0/1: (real == (pred>0.5)) <=> ((real>0.5)==(pred>0.5))
    bool ok = ((r[j].x > 0.5f) == (p[j].x > 0.5f)) &&
              ((r[j].y > 0.5f) == (p[j].y > 0.5f)) &&
              ((r[j].z > 0.5f) == (p[j].z > 0.5f)) &&
              ((r[j].w > 0.5f) == (p[j].w > 0.5f));
    // 64-bit wave ballot: bit i = lane i's half-row ok. Row ok = both halves ok.
    unsigned long long m = __ballot(ok);
    m &= (m >> 1);
    m &= 0x5555555555555555ULL;
    cnt += (unsigned int)__popcll(m);  // wave-uniform rows-matched this iter
  }

  // Combine the 4 waves of the block; one partial per block, no global atomic.
  __shared__ unsigned int wsum[BLOCK / 64];
  const int lane = threadIdx.x & 63;
  const int wave = threadIdx.x >> 6;
  if (lane == 0) wsum[wave] = cnt;
  __syncthreads();
  if (threadIdx.x == 0)
    partials[blockIdx.x] = wsum[0] + wsum[1] + wsum[2] + wsum[3];
}

__global__ __launch_bounds__(256) void finalize_loss(
    const unsigned int* __restrict__ partials, float* __restrict__ out) {
  const int t = threadIdx.x;
  unsigned int s = 0;
#pragma unroll
  for (int k = 0; k < GRID / 256; ++k) s += partials[t + k * 256];  // 4 coalesced loads
#pragma unroll
  for (int off = 32; off > 0; off >>= 1) s += __shfl_down(s, off, 64);

  __shared__ unsigned int wsum[4];
  if ((t & 63) == 0) wsum[t >> 6] = s;
  __syncthreads();
  if (t == 0)
    out[0] = 1.0f - (float)(wsum[0] + wsum[1] + wsum[2] + wsum[3]) *
                        (1.0f / (float)N_ROWS);
}

extern "C" void kernel_launch(void* const* d_in, const int* in_sizes, int n_in,
                              void* d_out, int out_size, void* d_ws, size_t ws_size,
                              hipStream_t stream) {
  const float4* real4 = (const float4*)d_in[0];
  const float4* pred4 = (const float4*)d_in[1];
  unsigned int* partials = (unsigned int*)d_ws;  // 1024 * 4 B = 4 KB scratch
  float* out = (float*)d_out;

  // Every partial slot is written by its block -> no memset node needed.
  row_match_count<<<GRID, BLOCK, 0, stream>>>(real4, pred4, partials);
  finalize_loss<<<1, 256, 0, stream>>>(partials, out);
}